// Round 1
// baseline (1567.689 us; speedup 1.0000x reference)
//
#include <hip/hip_runtime.h>
#include <cmath>

#define SEQ 2048
#define DDIM 1024
#define NROWS 8192   // B*S
#define KSEL 8
#define IMAXC 0x7fffffff

// ---------------------------------------------------------------------------
// k0: C[M,N] = sum_d A[d,i]*B[d,j]   (TN; A:[K,M], B:[K,N] row-major, f64 acc)
// BM=BN=64, BK=32, 256 threads, 4x4 micro-tile
// ---------------------------------------------------------------------------
__global__ __launch_bounds__(256)
void k0_gemm_tn(const float* __restrict__ A, const float* __restrict__ B,
                float* __restrict__ C, int M, int N, int K) {
  __shared__ __align__(16) float As[32][68];
  __shared__ __align__(16) float Bs[32][68];
  const int tid = threadIdx.x;
  const int tx = tid & 15, ty = tid >> 4;
  const int brow = blockIdx.y << 6;
  const int bcol = blockIdx.x << 6;
  double acc[4][4] = {};
  for (int k0 = 0; k0 < K; k0 += 32) {
#pragma unroll
    for (int i = 0; i < 2; ++i) {
      const int f = tid + (i << 8);
      const int r = f >> 4;           // 0..31 (k)
      const int c4 = (f & 15) << 2;   // 0..60 (m/n)
      *reinterpret_cast<float4*>(&As[r][c4]) =
          *reinterpret_cast<const float4*>(&A[(size_t)(k0 + r) * M + brow + c4]);
      *reinterpret_cast<float4*>(&Bs[r][c4]) =
          *reinterpret_cast<const float4*>(&B[(size_t)(k0 + r) * N + bcol + c4]);
    }
    __syncthreads();
#pragma unroll
    for (int kk = 0; kk < 32; ++kk) {
      const float4 a = *reinterpret_cast<const float4*>(&As[kk][ty << 2]);
      const float4 b = *reinterpret_cast<const float4*>(&Bs[kk][tx << 2]);
      const double ad[4] = {a.x, a.y, a.z, a.w};
      const double bd[4] = {b.x, b.y, b.z, b.w};
#pragma unroll
      for (int i = 0; i < 4; ++i)
#pragma unroll
        for (int j = 0; j < 4; ++j)
          acc[i][j] = fma(ad[i], bd[j], acc[i][j]);
    }
    __syncthreads();
  }
#pragma unroll
  for (int i = 0; i < 4; ++i) {
    float4 v = make_float4((float)acc[i][0], (float)acc[i][1],
                           (float)acc[i][2], (float)acc[i][3]);
    *reinterpret_cast<float4*>(
        &C[(size_t)(brow + (ty << 2) + i) * N + bcol + (tx << 2)]) = v;
  }
}

// ---------------------------------------------------------------------------
// k1: C[M,N] = sum_e A[i,e]*B[e,j]   (NN; A:[M,K], B:[K,N] row-major, f64 acc)
// ---------------------------------------------------------------------------
__global__ __launch_bounds__(256)
void k1_gemm_nn(const float* __restrict__ A, const float* __restrict__ B,
                float* __restrict__ C, int M, int N, int K) {
  __shared__ __align__(16) float As[32][68];  // [k][i] (transposed store)
  __shared__ __align__(16) float Bs[32][68];  // [k][j] (direct store)
  const int tid = threadIdx.x;
  const int tx = tid & 15, ty = tid >> 4;
  const int brow = blockIdx.y << 6;
  const int bcol = blockIdx.x << 6;
  double acc[4][4] = {};
  for (int k0 = 0; k0 < K; k0 += 32) {
#pragma unroll
    for (int i = 0; i < 2; ++i) {
      const int f = tid + (i << 8);
      // A tile: 64 rows x 32 k, transpose into As[k][row]
      const int r = f >> 3;          // 0..63 row
      const int c4 = (f & 7) << 2;   // 0..28 k
      const float4 va =
          *reinterpret_cast<const float4*>(&A[(size_t)(brow + r) * K + k0 + c4]);
      As[c4 + 0][r] = va.x; As[c4 + 1][r] = va.y;
      As[c4 + 2][r] = va.z; As[c4 + 3][r] = va.w;
      // B tile: 32 k x 64 cols, direct
      const int rb = f >> 4;          // 0..31 (k)
      const int cb4 = (f & 15) << 2;  // 0..60 (n)
      *reinterpret_cast<float4*>(&Bs[rb][cb4]) =
          *reinterpret_cast<const float4*>(&B[(size_t)(k0 + rb) * N + bcol + cb4]);
    }
    __syncthreads();
#pragma unroll
    for (int kk = 0; kk < 32; ++kk) {
      const float4 a = *reinterpret_cast<const float4*>(&As[kk][ty << 2]);
      const float4 b = *reinterpret_cast<const float4*>(&Bs[kk][tx << 2]);
      const double ad[4] = {a.x, a.y, a.z, a.w};
      const double bd[4] = {b.x, b.y, b.z, b.w};
#pragma unroll
      for (int i = 0; i < 4; ++i)
#pragma unroll
        for (int j = 0; j < 4; ++j)
          acc[i][j] = fma(ad[i], bd[j], acc[i][j]);
    }
    __syncthreads();
  }
#pragma unroll
  for (int i = 0; i < 4; ++i) {
    float4 v = make_float4((float)acc[i][0], (float)acc[i][1],
                           (float)acc[i][2], (float)acc[i][3]);
    *reinterpret_cast<float4*>(
        &C[(size_t)(brow + (ty << 2) + i) * N + bcol + (tx << 2)]) = v;
  }
}

// ---------------------------------------------------------------------------
// k2: fused scores + per-thread running top-8.
// scores[b][i][j] = sum_f T[b*S+i, f] * H[b*S+j, f]  (NT, f64 acc)
// grid (4 col-quarters, 32 row-blocks, 4 batches), 256 threads.
// Each block: 64 rows x 512 cols (8 tiles of 64). After each tile the 64x64
// score tile goes to LDS; thread t scans row t/4, cols (t%4)*16..+15, and
// maintains a stable (value desc, idx asc) top-8 in registers.
// ---------------------------------------------------------------------------
__global__ __launch_bounds__(256)
void k2_scores_topk(const float* __restrict__ T, const float* __restrict__ H,
                    float* __restrict__ cand_v, int* __restrict__ cand_i) {
  __shared__ __align__(16) float As[32][68];
  __shared__ __align__(16) float Bs[32][68];
  __shared__ float Sl[64][65];
  const int tid = threadIdx.x;
  const int tx = tid & 15, ty = tid >> 4;
  const int q = blockIdx.x;          // col quarter 0..3
  const int rb = blockIdx.y;         // row block 0..31
  const int b = blockIdx.z;          // batch
  const int row0 = b * SEQ + (rb << 6);
  const int sr = tid >> 2;           // scan row 0..63
  const int sc = (tid & 3) << 4;     // scan col offset within tile

  float t8v[KSEL];
  int t8i[KSEL];
#pragma unroll
  for (int p = 0; p < KSEL; ++p) { t8v[p] = -1.0f; t8i[p] = IMAXC; }

  for (int t = 0; t < 8; ++t) {
    const int lcol0 = (q << 9) + (t << 6);   // local col base 0..1984
    const int c0 = b * SEQ + lcol0;          // H row base
    double acc[4][4] = {};
    for (int k0 = 0; k0 < DDIM; k0 += 32) {
#pragma unroll
      for (int i = 0; i < 2; ++i) {
        const int f = tid + (i << 8);
        const int r = f >> 3;         // 0..63
        const int c4 = (f & 7) << 2;  // 0..28
        const float4 va = *reinterpret_cast<const float4*>(
            &T[(size_t)(row0 + r) * DDIM + k0 + c4]);
        As[c4 + 0][r] = va.x; As[c4 + 1][r] = va.y;
        As[c4 + 2][r] = va.z; As[c4 + 3][r] = va.w;
        const float4 vb = *reinterpret_cast<const float4*>(
            &H[(size_t)(c0 + r) * DDIM + k0 + c4]);
        Bs[c4 + 0][r] = vb.x; Bs[c4 + 1][r] = vb.y;
        Bs[c4 + 2][r] = vb.z; Bs[c4 + 3][r] = vb.w;
      }
      __syncthreads();
#pragma unroll
      for (int kk = 0; kk < 32; ++kk) {
        const float4 a = *reinterpret_cast<const float4*>(&As[kk][ty << 2]);
        const float4 bb = *reinterpret_cast<const float4*>(&Bs[kk][tx << 2]);
        const double ad[4] = {a.x, a.y, a.z, a.w};
        const double bd[4] = {bb.x, bb.y, bb.z, bb.w};
#pragma unroll
        for (int i = 0; i < 4; ++i)
#pragma unroll
          for (int j = 0; j < 4; ++j)
            acc[i][j] = fma(ad[i], bd[j], acc[i][j]);
      }
      __syncthreads();
    }
    // dump tile to LDS
#pragma unroll
    for (int i = 0; i < 4; ++i)
#pragma unroll
      for (int j = 0; j < 4; ++j)
        Sl[(ty << 2) + i][(tx << 2) + j] = (float)acc[i][j];
    __syncthreads();
    // scan 16 values, update register top-8 (stream idx increasing -> stable)
#pragma unroll
    for (int c = 0; c < 16; ++c) {
      const float aff = expf(Sl[sr][sc + c]);
      const int idx = lcol0 + sc + c;
      if (aff > t8v[KSEL - 1]) {
        float pv = aff; int pi = idx;
#pragma unroll
        for (int p = 0; p < KSEL; ++p) {
          if (aff > t8v[p]) {
            const float tv = t8v[p]; const int ti = t8i[p];
            t8v[p] = pv; t8i[p] = pi; pv = tv; pi = ti;
          }
        }
      }
    }
    __syncthreads();
  }
  // write 8 candidates: slot = row*128 + q*32 + (tid&3)*8
  const size_t grow = (size_t)(row0 + sr);
  const size_t slot = grow * 128 + (size_t)(q << 5) + (size_t)((tid & 3) << 3);
#pragma unroll
  for (int p = 0; p < KSEL; ++p) {
    cand_v[slot + p] = t8v[p];
    cand_i[slot + p] = t8i[p];
  }
}

// ---------------------------------------------------------------------------
// k3: exact merge of 128 candidates/row -> final top-8, weights, edge count.
// Full (value desc, idx asc) comparator => matches lax.top_k stable order.
// ---------------------------------------------------------------------------
__global__ __launch_bounds__(256)
void k3_merge(const float* __restrict__ cand_v, const int* __restrict__ cand_i,
              int* __restrict__ topi, float* __restrict__ topw,
              int* __restrict__ cnt) {
  const int r = blockIdx.x * 256 + threadIdx.x;
  if (r >= NROWS) return;
  const float* cv = &cand_v[(size_t)r * 128];
  const int* ci = &cand_i[(size_t)r * 128];
  float t8v[KSEL];
  int t8i[KSEL];
#pragma unroll
  for (int p = 0; p < KSEL; ++p) { t8v[p] = -1.0f; t8i[p] = IMAXC; }
  for (int s = 0; s < 128; ++s) {
    const float v = cv[s];
    const int id = ci[s];
    const bool g7 = (v > t8v[KSEL - 1]) ||
                    (v == t8v[KSEL - 1] && id < t8i[KSEL - 1]);
    if (g7) {
      float pv = v; int pi = id;
#pragma unroll
      for (int p = 0; p < KSEL; ++p) {
        const bool g = (v > t8v[p]) || (v == t8v[p] && id < t8i[p]);
        if (g) {
          const float tv = t8v[p]; const int ti = t8i[p];
          t8v[p] = pv; t8i[p] = pi; pv = tv; pi = ti;
        }
      }
    }
  }
  float sum = 0.0f;
#pragma unroll
  for (int p = 0; p < KSEL; ++p) sum += t8v[p];
  sum += 1e-8f;
  const int sloc = r & (SEQ - 1);
  int c = KSEL;
#pragma unroll
  for (int p = 0; p < KSEL; ++p)
    if (t8i[p] == sloc) --c;
  cnt[r] = c;
#pragma unroll
  for (int p = 0; p < KSEL; ++p) {
    topi[(size_t)r * KSEL + p] = t8i[p];
    topw[(size_t)r * KSEL + p] = t8v[p] / sum;
  }
}

// ---------------------------------------------------------------------------
// k4: exclusive prefix scan of per-row counts (8192 = 1024 threads x 8)
// ---------------------------------------------------------------------------
__global__ __launch_bounds__(1024)
void k4_scan(const int* __restrict__ cnt, int* __restrict__ off) {
  __shared__ int part[1024];
  const int t = threadIdx.x;
  int loc[8];
  int s = 0;
#pragma unroll
  for (int i = 0; i < 8; ++i) { loc[i] = s; s += cnt[t * 8 + i]; }
  part[t] = s;
  __syncthreads();
  for (int d = 1; d < 1024; d <<= 1) {
    const int add = (t >= d) ? part[t - d] : 0;
    __syncthreads();
    part[t] += add;
    __syncthreads();
  }
  const int base = (t == 0) ? 0 : part[t - 1];
#pragma unroll
  for (int i = 0; i < 8; ++i) off[t * 8 + i] = base + loc[i];
}

// ---------------------------------------------------------------------------
// k5: emit edges. out = [src(E) | dst(E) | w(E)] as float32 values.
// ---------------------------------------------------------------------------
__global__ __launch_bounds__(256)
void k5_emit(const int* __restrict__ topi, const float* __restrict__ topw,
             const int* __restrict__ off, float* __restrict__ out, int E) {
  const int r = blockIdx.x * 256 + threadIdx.x;
  if (r >= NROWS) return;
  const int o = off[r];
  const int sloc = r & (SEQ - 1);
  const int bbase = r & ~(SEQ - 1);
  int e = 0;
#pragma unroll
  for (int p = 0; p < KSEL; ++p) {
    const int id = topi[(size_t)r * KSEL + p];
    const float w = topw[(size_t)r * KSEL + p];
    if (id != sloc) {
      const int pos = o + e;
      if (pos < E) {
        out[pos] = (float)r;
        out[(size_t)E + pos] = (float)(bbase + id);
        out[2 * (size_t)E + pos] = w;
      }
      ++e;
    }
  }
}

// ---------------------------------------------------------------------------
extern "C" void kernel_launch(void* const* d_in, const int* in_sizes, int n_in,
                              void* d_out, int out_size, void* d_ws,
                              size_t ws_size, hipStream_t stream) {
  const float* H = (const float*)d_in[0];      // [4,2048,1024]
  const float* Wphi = (const float*)d_in[1];   // [1024,1024]
  const float* Wpsi = (const float*)d_in[2];   // [1024,1024]
  // d_in[3] = k (==8, fixed)
  float* out = (float*)d_out;
  const int E = out_size / 3;

  float* Wc = (float*)d_ws;                       // 1024*1024
  float* T = Wc + (size_t)1024 * 1024;            // 8192*1024
  float* cand_v = T + (size_t)NROWS * DDIM;       // 8192*128
  int* cand_i = (int*)(cand_v + (size_t)NROWS * 128);
  int* topi = cand_i + (size_t)NROWS * 128;       // 8192*8
  float* topw = (float*)(topi + (size_t)NROWS * KSEL);
  int* cnt = (int*)(topw + (size_t)NROWS * KSEL); // 8192
  int* off = cnt + NROWS;                         // 8192
  // total ~45 MB

  // Wc = Wphi^T * Wpsi   [1024,1024]
  k0_gemm_tn<<<dim3(16, 16), 256, 0, stream>>>(Wphi, Wpsi, Wc, 1024, 1024, 1024);
  // T = H * Wc           [8192,1024]
  k1_gemm_nn<<<dim3(16, 128), 256, 0, stream>>>(H, Wc, T, NROWS, DDIM, DDIM);
  // fused scores + topk candidates
  k2_scores_topk<<<dim3(4, 32, 4), 256, 0, stream>>>(T, H, cand_v, cand_i);
  // exact merge -> top8 + weights + counts
  k3_merge<<<dim3(NROWS / 256), 256, 0, stream>>>(cand_v, cand_i, topi, topw, cnt);
  // prefix scan of counts
  k4_scan<<<dim3(1), 1024, 0, stream>>>(cnt, off);
  // emit
  k5_emit<<<dim3(NROWS / 256), 256, 0, stream>>>(topi, topw, off, out, E);
}

// Round 2
// 1143.630 us; speedup vs baseline: 1.3708x; 1.3708x over previous
//
#include <hip/hip_runtime.h>
#include <cmath>

#define SEQ 2048
#define DDIM 1024
#define NROWS 8192   // B*S
#define KSEL 8
#define IMAXC 0x7fffffff

typedef __attribute__((ext_vector_type(8))) short bf16x8;
typedef __attribute__((ext_vector_type(4))) float f32x4;

__device__ __forceinline__ unsigned short f2bf(float f) {
  unsigned u = __builtin_bit_cast(unsigned, f);
  u = (u + 0x7fffu + ((u >> 16) & 1u)) >> 16;
  return (unsigned short)u;
}
__device__ __forceinline__ float bf2f(unsigned short h) {
  unsigned u = ((unsigned)h) << 16;
  return __builtin_bit_cast(float, u);
}

// ---------------------------------------------------------------------------
// k0: Wc = Wphi^T * Wpsi  (TN, f64 acc)  -- UNCHANGED from R1 (bitwise)
// ---------------------------------------------------------------------------
__global__ __launch_bounds__(256)
void k0_gemm_tn(const float* __restrict__ A, const float* __restrict__ B,
                float* __restrict__ C, int M, int N, int K) {
  __shared__ __align__(16) float As[32][68];
  __shared__ __align__(16) float Bs[32][68];
  const int tid = threadIdx.x;
  const int tx = tid & 15, ty = tid >> 4;
  const int brow = blockIdx.y << 6;
  const int bcol = blockIdx.x << 6;
  double acc[4][4] = {};
  for (int k0 = 0; k0 < K; k0 += 32) {
#pragma unroll
    for (int i = 0; i < 2; ++i) {
      const int f = tid + (i << 8);
      const int r = f >> 4;
      const int c4 = (f & 15) << 2;
      *reinterpret_cast<float4*>(&As[r][c4]) =
          *reinterpret_cast<const float4*>(&A[(size_t)(k0 + r) * M + brow + c4]);
      *reinterpret_cast<float4*>(&Bs[r][c4]) =
          *reinterpret_cast<const float4*>(&B[(size_t)(k0 + r) * N + bcol + c4]);
    }
    __syncthreads();
#pragma unroll
    for (int kk = 0; kk < 32; ++kk) {
      const float4 a = *reinterpret_cast<const float4*>(&As[kk][ty << 2]);
      const float4 b = *reinterpret_cast<const float4*>(&Bs[kk][tx << 2]);
      const double ad[4] = {a.x, a.y, a.z, a.w};
      const double bd[4] = {b.x, b.y, b.z, b.w};
#pragma unroll
      for (int i = 0; i < 4; ++i)
#pragma unroll
        for (int j = 0; j < 4; ++j)
          acc[i][j] = fma(ad[i], bd[j], acc[i][j]);
    }
    __syncthreads();
  }
#pragma unroll
  for (int i = 0; i < 4; ++i) {
    float4 v = make_float4((float)acc[i][0], (float)acc[i][1],
                           (float)acc[i][2], (float)acc[i][3]);
    *reinterpret_cast<float4*>(
        &C[(size_t)(brow + (ty << 2) + i) * N + bcol + (tx << 2)]) = v;
  }
}

// ---------------------------------------------------------------------------
// k1: T = H * Wc  (NN, f64 acc)  -- UNCHANGED from R1 (bitwise; defines T)
// ---------------------------------------------------------------------------
__global__ __launch_bounds__(256)
void k1_gemm_nn(const float* __restrict__ A, const float* __restrict__ B,
                float* __restrict__ C, int M, int N, int K) {
  __shared__ __align__(16) float As[32][68];
  __shared__ __align__(16) float Bs[32][68];
  const int tid = threadIdx.x;
  const int tx = tid & 15, ty = tid >> 4;
  const int brow = blockIdx.y << 6;
  const int bcol = blockIdx.x << 6;
  double acc[4][4] = {};
  for (int k0 = 0; k0 < K; k0 += 32) {
#pragma unroll
    for (int i = 0; i < 2; ++i) {
      const int f = tid + (i << 8);
      const int r = f >> 3;
      const int c4 = (f & 7) << 2;
      const float4 va =
          *reinterpret_cast<const float4*>(&A[(size_t)(brow + r) * K + k0 + c4]);
      As[c4 + 0][r] = va.x; As[c4 + 1][r] = va.y;
      As[c4 + 2][r] = va.z; As[c4 + 3][r] = va.w;
      const int rb = f >> 4;
      const int cb4 = (f & 15) << 2;
      *reinterpret_cast<float4*>(&Bs[rb][cb4]) =
          *reinterpret_cast<const float4*>(&B[(size_t)(k0 + rb) * N + bcol + cb4]);
    }
    __syncthreads();
#pragma unroll
    for (int kk = 0; kk < 32; ++kk) {
      const float4 a = *reinterpret_cast<const float4*>(&As[kk][ty << 2]);
      const float4 b = *reinterpret_cast<const float4*>(&Bs[kk][tx << 2]);
      const double ad[4] = {a.x, a.y, a.z, a.w};
      const double bd[4] = {b.x, b.y, b.z, b.w};
#pragma unroll
      for (int i = 0; i < 4; ++i)
#pragma unroll
        for (int j = 0; j < 4; ++j)
          acc[i][j] = fma(ad[i], bd[j], acc[i][j]);
    }
    __syncthreads();
  }
#pragma unroll
  for (int i = 0; i < 4; ++i) {
    float4 v = make_float4((float)acc[i][0], (float)acc[i][1],
                           (float)acc[i][2], (float)acc[i][3]);
    *reinterpret_cast<float4*>(
        &C[(size_t)(brow + (ty << 2) + i) * N + bcol + (tx << 2)]) = v;
  }
}

// ---------------------------------------------------------------------------
// kcvt: per-batch f32 -> bf16 (RNE) for T[b] and H[b]
// ---------------------------------------------------------------------------
__global__ __launch_bounds__(256)
void kcvt(const float* __restrict__ Tin, const float* __restrict__ Hin,
          unsigned short* __restrict__ Tb, unsigned short* __restrict__ Hb) {
  const int i = (blockIdx.x * 256 + threadIdx.x) << 3;  // 8 elems/thread
  {
    const float4 a0 = *reinterpret_cast<const float4*>(&Tin[i]);
    const float4 a1 = *reinterpret_cast<const float4*>(&Tin[i + 4]);
    uint4 o;
    o.x = f2bf(a0.x) | ((unsigned)f2bf(a0.y) << 16);
    o.y = f2bf(a0.z) | ((unsigned)f2bf(a0.w) << 16);
    o.z = f2bf(a1.x) | ((unsigned)f2bf(a1.y) << 16);
    o.w = f2bf(a1.z) | ((unsigned)f2bf(a1.w) << 16);
    *reinterpret_cast<uint4*>(&Tb[i]) = o;
  }
  {
    const float4 a0 = *reinterpret_cast<const float4*>(&Hin[i]);
    const float4 a1 = *reinterpret_cast<const float4*>(&Hin[i + 4]);
    uint4 o;
    o.x = f2bf(a0.x) | ((unsigned)f2bf(a0.y) << 16);
    o.y = f2bf(a0.z) | ((unsigned)f2bf(a0.w) << 16);
    o.z = f2bf(a1.x) | ((unsigned)f2bf(a1.y) << 16);
    o.w = f2bf(a1.z) | ((unsigned)f2bf(a1.w) << 16);
    *reinterpret_cast<uint4*>(&Hb[i]) = o;
  }
}

// ---------------------------------------------------------------------------
// k2_mfma: approx scores = Tb * Hb^T (one batch), 128x128 tile, 4 waves,
// mfma_f32_16x16x32_bf16, BK=64, slot-XOR LDS swizzle, fused epilogue:
// per-row top-8 within the block's 128 cols -> cand_v (bf16) / cand_i (u8).
// ---------------------------------------------------------------------------
__global__ __launch_bounds__(256)
void k2_mfma(const unsigned short* __restrict__ Tb,
             const unsigned short* __restrict__ Hb,
             unsigned short* __restrict__ cand_v,
             unsigned char* __restrict__ cand_i) {
  __shared__ union {
    unsigned short stage[2][128 * 64];  // [A|B][row 0..127][8 slots of 8 bf16]
    float Sl[64][130];
  } u;
  const int tid = threadIdx.x;
  const int lane = tid & 63;
  const int w = tid >> 6;
  const int wr = w >> 1, wc = w & 1;
  const int lr = lane & 15, lg = lane >> 4;
  const int brow = blockIdx.y << 7, bcol = blockIdx.x << 7;

  f32x4 acc[4][4];
#pragma unroll
  for (int mi = 0; mi < 4; ++mi)
#pragma unroll
    for (int nj = 0; nj < 4; ++nj)
      acc[mi][nj] = (f32x4){0.f, 0.f, 0.f, 0.f};

  for (int k0 = 0; k0 < DDIM; k0 += 64) {
    __syncthreads();
#pragma unroll
    for (int q = 0; q < 4; ++q) {
      const int c = (q << 8) + tid;          // 0..1023 linear 16B chunk
      const int row = c >> 3, slot = c & 7;
      const int gs = slot ^ (row & 7);       // inverse-swizzled source slot
      *reinterpret_cast<uint4*>(&u.stage[0][c << 3]) =
          *reinterpret_cast<const uint4*>(
              &Tb[(size_t)(brow + row) * DDIM + k0 + (gs << 3)]);
      *reinterpret_cast<uint4*>(&u.stage[1][c << 3]) =
          *reinterpret_cast<const uint4*>(
              &Hb[(size_t)(bcol + row) * DDIM + k0 + (gs << 3)]);
    }
    __syncthreads();
#pragma unroll
    for (int kh = 0; kh < 2; ++kh) {
      bf16x8 af[4], bf[4];
      const int sl = (kh << 2) + lg;
#pragma unroll
      for (int mi = 0; mi < 4; ++mi) {
        const int ra = (wr << 6) + (mi << 4) + lr;
        af[mi] = *reinterpret_cast<const bf16x8*>(
            &u.stage[0][(ra << 6) + ((sl ^ (ra & 7)) << 3)]);
        const int rb = (wc << 6) + (mi << 4) + lr;
        bf[mi] = *reinterpret_cast<const bf16x8*>(
            &u.stage[1][(rb << 6) + ((sl ^ (rb & 7)) << 3)]);
      }
#pragma unroll
      for (int mi = 0; mi < 4; ++mi)
#pragma unroll
        for (int nj = 0; nj < 4; ++nj)
          acc[mi][nj] = __builtin_amdgcn_mfma_f32_16x16x32_bf16(
              af[mi], bf[nj], acc[mi][nj], 0, 0, 0);
    }
  }

  // epilogue: two 64-row phases; dump to LDS, 64 threads scan 128 cols each
  const int bx = blockIdx.x;
  for (int p = 0; p < 2; ++p) {
    __syncthreads();
    if (wr == p) {
#pragma unroll
      for (int mi = 0; mi < 4; ++mi)
#pragma unroll
        for (int nj = 0; nj < 4; ++nj)
#pragma unroll
          for (int r = 0; r < 4; ++r)
            u.Sl[(mi << 4) + (lg << 2) + r][(wc << 6) + (nj << 4) + lr] =
                acc[mi][nj][r];
    }
    __syncthreads();
    if (tid < 64) {
      float v[KSEL];
      int ci[KSEL];
#pragma unroll
      for (int s = 0; s < KSEL; ++s) { v[s] = -3.0e38f; ci[s] = 0; }
      for (int c = 0; c < 128; ++c) {
        const float x = u.Sl[tid][c];
        if (x > v[KSEL - 1]) {
          float pv = x; int pc = c;
#pragma unroll
          for (int s = 0; s < KSEL; ++s) {
            if (x > v[s]) {
              const float tv = v[s]; const int tc = ci[s];
              v[s] = pv; ci[s] = pc; pv = tv; pc = tc;
            }
          }
        }
      }
      const size_t base = (size_t)(brow + (p << 6) + tid) * 128 + ((size_t)bx << 3);
#pragma unroll
      for (int s = 0; s < KSEL; ++s) {
        cand_v[base + s] = f2bf(v[s]);
        cand_i[base + s] = (unsigned char)ci[s];
      }
    }
  }
}

// ---------------------------------------------------------------------------
// kx_extract: per row, wave-parallel extraction of approx-top-16 indices
// from the 128 block-candidates (2 per lane, sorted; 16 rounds of wave-max).
// ---------------------------------------------------------------------------
__global__ __launch_bounds__(256)
void kx_extract(const unsigned short* __restrict__ cand_v,
                const unsigned char* __restrict__ cand_i,
                unsigned short* __restrict__ cand16) {
  const int tid = threadIdx.x, lane = tid & 63, w = tid >> 6;
  const int r = blockIdx.x * 4 + w;
  const size_t base = (size_t)r * 128;
  const int s0 = lane << 1, s1 = s0 + 1;
  float v0 = bf2f(cand_v[base + s0]);
  float v1 = bf2f(cand_v[base + s1]);
  int i0 = ((s0 >> 3) << 7) + cand_i[base + s0];
  int i1 = ((s1 >> 3) << 7) + cand_i[base + s1];
  if (v1 > v0) {
    const float tv = v0; v0 = v1; v1 = tv;
    const int ti = i0; i0 = i1; i1 = ti;
  }
  int keep = 0;
  for (int rnd = 0; rnd < 16; ++rnd) {
    float m = v0;
#pragma unroll
    for (int off = 32; off >= 1; off >>= 1) m = fmaxf(m, __shfl_xor(m, off));
    const unsigned long long bm = __ballot(v0 == m);
    const int owner = __ffsll(bm) - 1;
    const int oi = __shfl(i0, owner);
    if (lane == owner) { v0 = v1; i0 = i1; v1 = -3.0e38f; }
    if (lane == rnd) keep = oi;
  }
  if (lane < 16) cand16[(size_t)r * 16 + lane] = (unsigned short)keep;
}

// ---------------------------------------------------------------------------
// kr_rescore: exact f64 rescore of the 16 candidates; expf; stable top-8
// (value desc, idx asc); weights + self-loop count.  One wave per row.
// ---------------------------------------------------------------------------
__global__ __launch_bounds__(256)
void kr_rescore(const float* __restrict__ T, const float* __restrict__ H,
                const unsigned short* __restrict__ cand16,
                int* __restrict__ topi, float* __restrict__ topw,
                int* __restrict__ cnt) {
  const int tid = threadIdx.x, lane = tid & 63, w = tid >> 6;
  const int r = blockIdx.x * 4 + w;
  const int b = r >> 11, iloc = r & (SEQ - 1);
  const float* Trow = T + (size_t)r * DDIM;
  float4 t4[4];
#pragma unroll
  for (int q = 0; q < 4; ++q)
    t4[q] = *reinterpret_cast<const float4*>(&Trow[(q << 8) + (lane << 2)]);

  float t8v[KSEL];
  int t8i[KSEL];
#pragma unroll
  for (int p = 0; p < KSEL; ++p) { t8v[p] = -1.0f; t8i[p] = IMAXC; }

  for (int c = 0; c < 16; ++c) {
    const int j = cand16[(size_t)r * 16 + c];
    const float* Hrow = H + ((size_t)(b << 11) + j) * DDIM;
    double s = 0.0;
#pragma unroll
    for (int q = 0; q < 4; ++q) {
      const float4 h = *reinterpret_cast<const float4*>(&Hrow[(q << 8) + (lane << 2)]);
      s = fma((double)t4[q].x, (double)h.x, s);
      s = fma((double)t4[q].y, (double)h.y, s);
      s = fma((double)t4[q].z, (double)h.z, s);
      s = fma((double)t4[q].w, (double)h.w, s);
    }
#pragma unroll
    for (int off = 1; off < 64; off <<= 1) s += __shfl_xor(s, off);
    const float aff = expf((float)s);
    const bool g7 = (aff > t8v[KSEL - 1]) ||
                    (aff == t8v[KSEL - 1] && j < t8i[KSEL - 1]);
    if (g7) {
      float pv = aff; int pi = j;
#pragma unroll
      for (int p = 0; p < KSEL; ++p) {
        const bool g = (aff > t8v[p]) || (aff == t8v[p] && j < t8i[p]);
        if (g) {
          const float tv = t8v[p]; const int ti = t8i[p];
          t8v[p] = pv; t8i[p] = pi; pv = tv; pi = ti;
        }
      }
    }
  }
  if (lane == 0) {
    float sum = 0.0f;
#pragma unroll
    for (int p = 0; p < KSEL; ++p) sum += t8v[p];
    sum += 1e-8f;
    int c8 = KSEL;
#pragma unroll
    for (int p = 0; p < KSEL; ++p)
      if (t8i[p] == iloc) --c8;
    cnt[r] = c8;
#pragma unroll
    for (int p = 0; p < KSEL; ++p) {
      topi[(size_t)r * KSEL + p] = t8i[p];
      topw[(size_t)r * KSEL + p] = t8v[p] / sum;
    }
  }
}

// ---------------------------------------------------------------------------
// k4: exclusive prefix scan of per-row counts  -- UNCHANGED from R1
// ---------------------------------------------------------------------------
__global__ __launch_bounds__(1024)
void k4_scan(const int* __restrict__ cnt, int* __restrict__ off) {
  __shared__ int part[1024];
  const int t = threadIdx.x;
  int loc[8];
  int s = 0;
#pragma unroll
  for (int i = 0; i < 8; ++i) { loc[i] = s; s += cnt[t * 8 + i]; }
  part[t] = s;
  __syncthreads();
  for (int d = 1; d < 1024; d <<= 1) {
    const int add = (t >= d) ? part[t - d] : 0;
    __syncthreads();
    part[t] += add;
    __syncthreads();
  }
  const int base = (t == 0) ? 0 : part[t - 1];
#pragma unroll
  for (int i = 0; i < 8; ++i) off[t * 8 + i] = base + loc[i];
}

// ---------------------------------------------------------------------------
// k5: emit edges  -- UNCHANGED from R1
// ---------------------------------------------------------------------------
__global__ __launch_bounds__(256)
void k5_emit(const int* __restrict__ topi, const float* __restrict__ topw,
             const int* __restrict__ off, float* __restrict__ out, int E) {
  const int r = blockIdx.x * 256 + threadIdx.x;
  if (r >= NROWS) return;
  const int o = off[r];
  const int sloc = r & (SEQ - 1);
  const int bbase = r & ~(SEQ - 1);
  int e = 0;
#pragma unroll
  for (int p = 0; p < KSEL; ++p) {
    const int id = topi[(size_t)r * KSEL + p];
    const float w = topw[(size_t)r * KSEL + p];
    if (id != sloc) {
      const int pos = o + e;
      if (pos < E) {
        out[pos] = (float)r;
        out[(size_t)E + pos] = (float)(bbase + id);
        out[2 * (size_t)E + pos] = w;
      }
      ++e;
    }
  }
}

// ---------------------------------------------------------------------------
extern "C" void kernel_launch(void* const* d_in, const int* in_sizes, int n_in,
                              void* d_out, int out_size, void* d_ws,
                              size_t ws_size, hipStream_t stream) {
  const float* H = (const float*)d_in[0];      // [4,2048,1024]
  const float* Wphi = (const float*)d_in[1];   // [1024,1024]
  const float* Wpsi = (const float*)d_in[2];   // [1024,1024]
  float* out = (float*)d_out;
  const int E = out_size / 3;

  // workspace layout (45.94 MB total; R1 proved >= 46.7 MB available)
  char* base = (char*)d_ws;
  float* T = (float*)base;                               // 33,554,432 B
  char* regionX = base + 33554432;                       //  8,388,608 B
  float* Wc = (float*)regionX;                           //  (overlapped)
  unsigned short* Tb = (unsigned short*)regionX;         //  4,194,304 B
  unsigned short* Hb = (unsigned short*)(regionX + 4194304);
  char* pp = regionX + 8388608;
  unsigned short* cand_v = (unsigned short*)pp; pp += 2097152;   // bf16
  unsigned char* cand_i = (unsigned char*)pp;  pp += 1048576;    // u8 local col
  unsigned short* cand16 = (unsigned short*)pp; pp += 262144;    // u16 col
  int* topi = (int*)pp;  pp += 262144;
  float* topw = (float*)pp; pp += 262144;
  int* cnt = (int*)pp;   pp += 32768;
  int* off = (int*)pp;

  // Wc = Wphi^T * Wpsi
  k0_gemm_tn<<<dim3(16, 16), 256, 0, stream>>>(Wphi, Wpsi, Wc, 1024, 1024, 1024);
  // T = H * Wc  (bitwise-identical to R1; defines the exact ranking)
  k1_gemm_nn<<<dim3(16, 128), 256, 0, stream>>>(H, Wc, T, NROWS, DDIM, DDIM);

  // per batch: bf16 convert + approx MFMA scores with fused block-top-8
  for (int b = 0; b < 4; ++b) {
    const size_t boff = (size_t)b * SEQ * DDIM;
    kcvt<<<1024, 256, 0, stream>>>(T + boff, H + boff, Tb, Hb);
    k2_mfma<<<dim3(16, 16), 256, 0, stream>>>(
        Tb, Hb, cand_v + (size_t)b * SEQ * 128, cand_i + (size_t)b * SEQ * 128);
  }
  // approx-top-16 per row
  kx_extract<<<NROWS / 4, 256, 0, stream>>>(cand_v, cand_i, cand16);
  // exact f64 rescore + stable top-8 + weights + counts
  kr_rescore<<<NROWS / 4, 256, 0, stream>>>(T, H, cand16, topi, topw, cnt);
  // prefix scan + emit
  k4_scan<<<dim3(1), 1024, 0, stream>>>(cnt, off);
  k5_emit<<<dim3(NROWS / 256), 256, 0, stream>>>(topi, topw, off, out, E);
}

// Round 3
// 824.736 us; speedup vs baseline: 1.9008x; 1.3867x over previous
//
#include <hip/hip_runtime.h>
#include <cmath>

#define SEQ 2048
#define DDIM 1024
#define NROWS 8192   // B*S
#define KSEL 8
#define IMAXC 0x7fffffff

typedef __attribute__((ext_vector_type(8))) short bf16x8;
typedef __attribute__((ext_vector_type(4))) float f32x4;

__device__ __forceinline__ unsigned short f2bf(float f) {
  unsigned u = __builtin_bit_cast(unsigned, f);
  u = (u + 0x7fffu + ((u >> 16) & 1u)) >> 16;
  return (unsigned short)u;
}
__device__ __forceinline__ float bf2f(unsigned short h) {
  unsigned u = ((unsigned)h) << 16;
  return __builtin_bit_cast(float, u);
}
__device__ __forceinline__ unsigned pkbf(float a, float b) {
  unsigned r;
  asm("v_cvt_pk_bf16_f32 %0, %1, %2" : "=v"(r) : "v"(a), "v"(b));
  return r;
}

// ---------------------------------------------------------------------------
// k0: Wc = Wphi^T * Wpsi  (TN, f64 acc, f32 out) -- UNCHANGED (bitwise)
// ---------------------------------------------------------------------------
__global__ __launch_bounds__(256)
void k0_gemm_tn(const float* __restrict__ A, const float* __restrict__ B,
                float* __restrict__ C, int M, int N, int K) {
  __shared__ __align__(16) float As[32][68];
  __shared__ __align__(16) float Bs[32][68];
  const int tid = threadIdx.x;
  const int tx = tid & 15, ty = tid >> 4;
  const int brow = blockIdx.y << 6;
  const int bcol = blockIdx.x << 6;
  double acc[4][4] = {};
  for (int k0 = 0; k0 < K; k0 += 32) {
#pragma unroll
    for (int i = 0; i < 2; ++i) {
      const int f = tid + (i << 8);
      const int r = f >> 4;
      const int c4 = (f & 15) << 2;
      *reinterpret_cast<float4*>(&As[r][c4]) =
          *reinterpret_cast<const float4*>(&A[(size_t)(k0 + r) * M + brow + c4]);
      *reinterpret_cast<float4*>(&Bs[r][c4]) =
          *reinterpret_cast<const float4*>(&B[(size_t)(k0 + r) * N + bcol + c4]);
    }
    __syncthreads();
#pragma unroll
    for (int kk = 0; kk < 32; ++kk) {
      const float4 a = *reinterpret_cast<const float4*>(&As[kk][ty << 2]);
      const float4 b = *reinterpret_cast<const float4*>(&Bs[kk][tx << 2]);
      const double ad[4] = {a.x, a.y, a.z, a.w};
      const double bd[4] = {b.x, b.y, b.z, b.w};
#pragma unroll
      for (int i = 0; i < 4; ++i)
#pragma unroll
        for (int j = 0; j < 4; ++j)
          acc[i][j] = fma(ad[i], bd[j], acc[i][j]);
    }
    __syncthreads();
  }
#pragma unroll
  for (int i = 0; i < 4; ++i) {
    float4 v = make_float4((float)acc[i][0], (float)acc[i][1],
                           (float)acc[i][2], (float)acc[i][3]);
    *reinterpret_cast<float4*>(
        &C[(size_t)(brow + (ty << 2) + i) * N + bcol + (tx << 2)]) = v;
  }
}

// ---------------------------------------------------------------------------
// k1_fast: T = H * Wc (NN). Same f64 fma chain per output (k ascending,
// exact f32->f64 operands) => BITWISE-identical T to R1/R2's k1.
// 128x128 block, 8x8 micro-tile, BK=16, f64 operands staged in LDS.
// ---------------------------------------------------------------------------
__global__ __launch_bounds__(256)
void k1_fast(const float* __restrict__ A, const float* __restrict__ B,
             float* __restrict__ C) {
  __shared__ double As[16][130];  // [k][row], f64
  __shared__ double Bs[16][130];  // [k][col], f64
  const int tid = threadIdx.x;
  const int brow = blockIdx.y << 7;
  const int bcol = blockIdx.x << 7;
  const int tx = tid & 15;    // col group: cols tx + 16*j
  const int tyg = tid >> 4;   // row group: rows tyg*8 + i
  const int ar = tid >> 1, aks = (tid & 1) << 3;   // A staging map
  const int bk = tid >> 4, bc0 = (tid & 15) << 3;  // B staging map
  double acc[8][8];
#pragma unroll
  for (int i = 0; i < 8; ++i)
#pragma unroll
    for (int j = 0; j < 8; ++j) acc[i][j] = 0.0;

  const float* Aptr = &A[(size_t)(brow + ar) * DDIM + aks];
  const float* Bptr = &B[(size_t)bk * DDIM + bcol + bc0];

  for (int k0 = 0; k0 < DDIM; k0 += 16) {
    const float4 a0 = *reinterpret_cast<const float4*>(Aptr + k0);
    const float4 a1 = *reinterpret_cast<const float4*>(Aptr + k0 + 4);
    const float4 b0 = *reinterpret_cast<const float4*>(Bptr + (size_t)k0 * DDIM);
    const float4 b1 = *reinterpret_cast<const float4*>(Bptr + (size_t)k0 * DDIM + 4);
    __syncthreads();
    As[aks + 0][ar] = (double)a0.x; As[aks + 1][ar] = (double)a0.y;
    As[aks + 2][ar] = (double)a0.z; As[aks + 3][ar] = (double)a0.w;
    As[aks + 4][ar] = (double)a1.x; As[aks + 5][ar] = (double)a1.y;
    As[aks + 6][ar] = (double)a1.z; As[aks + 7][ar] = (double)a1.w;
    Bs[bk][bc0 + 0] = (double)b0.x; Bs[bk][bc0 + 1] = (double)b0.y;
    Bs[bk][bc0 + 2] = (double)b0.z; Bs[bk][bc0 + 3] = (double)b0.w;
    Bs[bk][bc0 + 4] = (double)b1.x; Bs[bk][bc0 + 5] = (double)b1.y;
    Bs[bk][bc0 + 6] = (double)b1.z; Bs[bk][bc0 + 7] = (double)b1.w;
    __syncthreads();
#pragma unroll 2
    for (int kk = 0; kk < 16; ++kk) {
      double a[8], b[8];
#pragma unroll
      for (int i = 0; i < 8; ++i) a[i] = As[kk][(tyg << 3) + i];
#pragma unroll
      for (int j = 0; j < 8; ++j) b[j] = Bs[kk][tx + (j << 4)];
#pragma unroll
      for (int i = 0; i < 8; ++i)
#pragma unroll
        for (int j = 0; j < 8; ++j)
          acc[i][j] = fma(a[i], b[j], acc[i][j]);
    }
  }
#pragma unroll
  for (int i = 0; i < 8; ++i) {
    float* crow = &C[(size_t)(brow + (tyg << 3) + i) * DDIM + bcol + tx];
#pragma unroll
    for (int j = 0; j < 8; ++j) crow[j << 4] = (float)acc[i][j];
  }
}

// ---------------------------------------------------------------------------
// k2_mfma: approx scores = bf16(T) * bf16(H)^T, all batches in one launch,
// grid (16 colblk, 16 rowblk, 4 batch). 128x128 tile, 4 waves, BK=64,
// slot-XOR LDS swizzle, f32->bf16 cvt in staging (v_cvt_pk_bf16_f32).
// Fused epilogue: per-row top-8 within block's 128 cols.
// ---------------------------------------------------------------------------
__global__ __launch_bounds__(256)
void k2_mfma(const float* __restrict__ T, const float* __restrict__ H,
             unsigned short* __restrict__ cand_v,
             unsigned char* __restrict__ cand_i) {
  __shared__ union {
    unsigned short stage[2][128 * 64];
    float Sl[64][130];
  } u;
  const int tid = threadIdx.x;
  const int lane = tid & 63;
  const int w = tid >> 6;
  const int wr = w >> 1, wc = w & 1;
  const int lr = lane & 15, lg = lane >> 4;
  const int z = blockIdx.z;
  const int brow = blockIdx.y << 7, bcol = blockIdx.x << 7;
  const int row0g = z * SEQ + brow;   // global T row base
  const int col0g = z * SEQ + bcol;   // global H row base

  f32x4 acc[4][4];
#pragma unroll
  for (int mi = 0; mi < 4; ++mi)
#pragma unroll
    for (int nj = 0; nj < 4; ++nj)
      acc[mi][nj] = (f32x4){0.f, 0.f, 0.f, 0.f};

  for (int k0 = 0; k0 < DDIM; k0 += 64) {
    __syncthreads();
#pragma unroll
    for (int q = 0; q < 4; ++q) {
      const int c = (q << 8) + tid;          // 0..1023 linear 16B chunk
      const int row = c >> 3, slot = c & 7;
      const int gs = slot ^ (row & 7);       // inverse-swizzled source slot
      {
        const float* s = &T[(size_t)(row0g + row) * DDIM + k0 + (gs << 3)];
        const float4 f0 = *reinterpret_cast<const float4*>(s);
        const float4 f1 = *reinterpret_cast<const float4*>(s + 4);
        uint4 o;
        o.x = pkbf(f0.x, f0.y); o.y = pkbf(f0.z, f0.w);
        o.z = pkbf(f1.x, f1.y); o.w = pkbf(f1.z, f1.w);
        *reinterpret_cast<uint4*>(&u.stage[0][c << 3]) = o;
      }
      {
        const float* s = &H[(size_t)(col0g + row) * DDIM + k0 + (gs << 3)];
        const float4 f0 = *reinterpret_cast<const float4*>(s);
        const float4 f1 = *reinterpret_cast<const float4*>(s + 4);
        uint4 o;
        o.x = pkbf(f0.x, f0.y); o.y = pkbf(f0.z, f0.w);
        o.z = pkbf(f1.x, f1.y); o.w = pkbf(f1.z, f1.w);
        *reinterpret_cast<uint4*>(&u.stage[1][c << 3]) = o;
      }
    }
    __syncthreads();
#pragma unroll
    for (int kh = 0; kh < 2; ++kh) {
      bf16x8 af[4], bf[4];
      const int sl = (kh << 2) + lg;
#pragma unroll
      for (int mi = 0; mi < 4; ++mi) {
        const int ra = (wr << 6) + (mi << 4) + lr;
        af[mi] = *reinterpret_cast<const bf16x8*>(
            &u.stage[0][(ra << 6) + ((sl ^ (ra & 7)) << 3)]);
        const int rb = (wc << 6) + (mi << 4) + lr;
        bf[mi] = *reinterpret_cast<const bf16x8*>(
            &u.stage[1][(rb << 6) + ((sl ^ (rb & 7)) << 3)]);
      }
#pragma unroll
      for (int mi = 0; mi < 4; ++mi)
#pragma unroll
        for (int nj = 0; nj < 4; ++nj)
          acc[mi][nj] = __builtin_amdgcn_mfma_f32_16x16x32_bf16(
              af[mi], bf[nj], acc[mi][nj], 0, 0, 0);
    }
  }

  // epilogue: two 64-row phases; dump to LDS, 64 threads scan 128 cols each
  const int bx = blockIdx.x;
  for (int p = 0; p < 2; ++p) {
    __syncthreads();
    if (wr == p) {
#pragma unroll
      for (int mi = 0; mi < 4; ++mi)
#pragma unroll
        for (int nj = 0; nj < 4; ++nj)
#pragma unroll
          for (int r = 0; r < 4; ++r)
            u.Sl[(mi << 4) + (lg << 2) + r][(wc << 6) + (nj << 4) + lr] =
                acc[mi][nj][r];
    }
    __syncthreads();
    if (tid < 64) {
      float v[KSEL];
      int ci[KSEL];
#pragma unroll
      for (int s = 0; s < KSEL; ++s) { v[s] = -3.0e38f; ci[s] = 0; }
      for (int c = 0; c < 128; ++c) {
        const float x = u.Sl[tid][c];
        if (x > v[KSEL - 1]) {
          float pv = x; int pc = c;
#pragma unroll
          for (int s = 0; s < KSEL; ++s) {
            if (x > v[s]) {
              const float tv = v[s]; const int tc = ci[s];
              v[s] = pv; ci[s] = pc; pv = tv; pc = tc;
            }
          }
        }
      }
      const size_t base =
          (size_t)(row0g + (p << 6) + tid) * 128 + ((size_t)bx << 3);
#pragma unroll
      for (int s = 0; s < KSEL; ++s) {
        cand_v[base + s] = f2bf(v[s]);
        cand_i[base + s] = (unsigned char)ci[s];
      }
    }
  }
}

// ---------------------------------------------------------------------------
// kr_rescore: fused (a) wave-parallel extraction of approx-top-16 from the
// 128 block-candidates, (b) exact f64 rescore, stable top-8 (value desc,
// idx asc), weights + self-loop count. One wave per row.
// ---------------------------------------------------------------------------
__global__ __launch_bounds__(256)
void kr_rescore(const float* __restrict__ T, const float* __restrict__ H,
                const unsigned short* __restrict__ cand_v,
                const unsigned char* __restrict__ cand_i,
                int* __restrict__ topi, float* __restrict__ topw,
                int* __restrict__ cnt) {
  const int tid = threadIdx.x, lane = tid & 63, w = tid >> 6;
  const int r = blockIdx.x * 4 + w;
  const int b = r >> 11, iloc = r & (SEQ - 1);

  // --- extraction (identical math to R2's kx_extract) ---
  const size_t cbase = (size_t)r * 128;
  const int s0 = lane << 1, s1 = s0 + 1;
  float v0 = bf2f(cand_v[cbase + s0]);
  float v1 = bf2f(cand_v[cbase + s1]);
  int i0 = ((s0 >> 3) << 7) + cand_i[cbase + s0];
  int i1 = ((s1 >> 3) << 7) + cand_i[cbase + s1];
  if (v1 > v0) {
    const float tv = v0; v0 = v1; v1 = tv;
    const int ti = i0; i0 = i1; i1 = ti;
  }
  int keep = 0;
  for (int rnd = 0; rnd < 16; ++rnd) {
    float m = v0;
#pragma unroll
    for (int off = 32; off >= 1; off >>= 1) m = fmaxf(m, __shfl_xor(m, off));
    const unsigned long long bm = __ballot(v0 == m);
    const int owner = __ffsll(bm) - 1;
    const int oi = __shfl(i0, owner);
    if (lane == owner) { v0 = v1; i0 = i1; v1 = -3.0e38f; }
    if (lane == rnd) keep = oi;
  }

  // --- exact rescore ---
  const float* Trow = T + (size_t)r * DDIM;
  float4 t4[4];
#pragma unroll
  for (int q = 0; q < 4; ++q)
    t4[q] = *reinterpret_cast<const float4*>(&Trow[(q << 8) + (lane << 2)]);

  float t8v[KSEL];
  int t8i[KSEL];
#pragma unroll
  for (int p = 0; p < KSEL; ++p) { t8v[p] = -1.0f; t8i[p] = IMAXC; }

  for (int c = 0; c < 16; ++c) {
    const int j = __shfl(keep, c);
    const float* Hrow = H + ((size_t)(b << 11) + j) * DDIM;
    double s = 0.0;
#pragma unroll
    for (int q = 0; q < 4; ++q) {
      const float4 h = *reinterpret_cast<const float4*>(&Hrow[(q << 8) + (lane << 2)]);
      s = fma((double)t4[q].x, (double)h.x, s);
      s = fma((double)t4[q].y, (double)h.y, s);
      s = fma((double)t4[q].z, (double)h.z, s);
      s = fma((double)t4[q].w, (double)h.w, s);
    }
#pragma unroll
    for (int off = 1; off < 64; off <<= 1) s += __shfl_xor(s, off);
    const float aff = expf((float)s);
    const bool g7 = (aff > t8v[KSEL - 1]) ||
                    (aff == t8v[KSEL - 1] && j < t8i[KSEL - 1]);
    if (g7) {
      float pv = aff; int pi = j;
#pragma unroll
      for (int p = 0; p < KSEL; ++p) {
        const bool g = (aff > t8v[p]) || (aff == t8v[p] && j < t8i[p]);
        if (g) {
          const float tv = t8v[p]; const int ti = t8i[p];
          t8v[p] = pv; t8i[p] = pi; pv = tv; pi = ti;
        }
      }
    }
  }
  if (lane == 0) {
    float sum = 0.0f;
#pragma unroll
    for (int p = 0; p < KSEL; ++p) sum += t8v[p];
    sum += 1e-8f;
    int c8 = KSEL;
#pragma unroll
    for (int p = 0; p < KSEL; ++p)
      if (t8i[p] == iloc) --c8;
    cnt[r] = c8;
#pragma unroll
    for (int p = 0; p < KSEL; ++p) {
      topi[(size_t)r * KSEL + p] = t8i[p];
      topw[(size_t)r * KSEL + p] = t8v[p] / sum;
    }
  }
}

// ---------------------------------------------------------------------------
// k4: exclusive prefix scan of per-row counts  -- UNCHANGED
// ---------------------------------------------------------------------------
__global__ __launch_bounds__(1024)
void k4_scan(const int* __restrict__ cnt, int* __restrict__ off) {
  __shared__ int part[1024];
  const int t = threadIdx.x;
  int loc[8];
  int s = 0;
#pragma unroll
  for (int i = 0; i < 8; ++i) { loc[i] = s; s += cnt[t * 8 + i]; }
  part[t] = s;
  __syncthreads();
  for (int d = 1; d < 1024; d <<= 1) {
    const int add = (t >= d) ? part[t - d] : 0;
    __syncthreads();
    part[t] += add;
    __syncthreads();
  }
  const int base = (t == 0) ? 0 : part[t - 1];
#pragma unroll
  for (int i = 0; i < 8; ++i) off[t * 8 + i] = base + loc[i];
}

// ---------------------------------------------------------------------------
// k5: emit edges  -- UNCHANGED
// ---------------------------------------------------------------------------
__global__ __launch_bounds__(256)
void k5_emit(const int* __restrict__ topi, const float* __restrict__ topw,
             const int* __restrict__ off, float* __restrict__ out, int E) {
  const int r = blockIdx.x * 256 + threadIdx.x;
  if (r >= NROWS) return;
  const int o = off[r];
  const int sloc = r & (SEQ - 1);
  const int bbase = r & ~(SEQ - 1);
  int e = 0;
#pragma unroll
  for (int p = 0; p < KSEL; ++p) {
    const int id = topi[(size_t)r * KSEL + p];
    const float w = topw[(size_t)r * KSEL + p];
    if (id != sloc) {
      const int pos = o + e;
      if (pos < E) {
        out[pos] = (float)r;
        out[(size_t)E + pos] = (float)(bbase + id);
        out[2 * (size_t)E + pos] = w;
      }
      ++e;
    }
  }
}

// ---------------------------------------------------------------------------
extern "C" void kernel_launch(void* const* d_in, const int* in_sizes, int n_in,
                              void* d_out, int out_size, void* d_ws,
                              size_t ws_size, hipStream_t stream) {
  const float* H = (const float*)d_in[0];      // [4,2048,1024]
  const float* Wphi = (const float*)d_in[1];   // [1024,1024]
  const float* Wpsi = (const float*)d_in[2];   // [1024,1024]
  float* out = (float*)d_out;
  const int E = out_size / 3;

  // workspace layout (~36.6 MB; R1 proved >= 46.7 MB available)
  char* base = (char*)d_ws;
  float* T = (float*)base;                         // 32 MB
  char* regionX = base + 33554432;                 // 4 MB shared region:
  float* Wc = (float*)regionX;                     //   Wc (dead after k1)
  unsigned short* cand_v = (unsigned short*)regionX;       // 2 MB (after k1)
  unsigned char* cand_i = (unsigned char*)(regionX + 2097152); // 1 MB
  char* pp = regionX + 4194304;
  int* topi = (int*)pp;  pp += 262144;
  float* topw = (float*)pp; pp += 262144;
  int* cnt = (int*)pp;   pp += 32768;
  int* off = (int*)pp;

  // Wc = Wphi^T * Wpsi
  k0_gemm_tn<<<dim3(16, 16), 256, 0, stream>>>(Wphi, Wpsi, Wc, 1024, 1024, 1024);
  // T = H * Wc  (bitwise-identical values to R1/R2; defines the exact ranking)
  k1_fast<<<dim3(8, 64), 256, 0, stream>>>(H, Wc, T);
  // approx MFMA scores + fused block-top-8, all batches (Wc is dead now;
  // cand_v/cand_i reuse its region)
  k2_mfma<<<dim3(16, 16, 4), 256, 0, stream>>>(T, H, cand_v, cand_i);
  // fused extraction + exact f64 rescore + stable top-8 + weights + counts
  kr_rescore<<<dim3(NROWS / 4), 256, 0, stream>>>(T, H, cand_v, cand_i,
                                                  topi, topw, cnt);
  // prefix scan + emit
  k4_scan<<<dim3(1), 1024, 0, stream>>>(cnt, off);
  k5_emit<<<dim3(NROWS / 256), 256, 0, stream>>>(topi, topw, off, out, E);
}

// Round 4
// 719.496 us; speedup vs baseline: 2.1789x; 1.1463x over previous
//
#include <hip/hip_runtime.h>
#include <cmath>

#define SEQ 2048
#define DDIM 1024
#define NROWS 8192   // B*S
#define KSEL 8
#define IMAXC 0x7fffffff

typedef __attribute__((ext_vector_type(8))) short bf16x8;
typedef __attribute__((ext_vector_type(4))) float f32x4;

__device__ __forceinline__ unsigned short f2bf(float f) {
  unsigned u = __builtin_bit_cast(unsigned, f);
  u = (u + 0x7fffu + ((u >> 16) & 1u)) >> 16;
  return (unsigned short)u;
}
__device__ __forceinline__ float bf2f(unsigned short h) {
  unsigned u = ((unsigned)h) << 16;
  return __builtin_bit_cast(float, u);
}
__device__ __forceinline__ unsigned pkbf(float a, float b) {
  unsigned r;
  asm("v_cvt_pk_bf16_f32 %0, %1, %2" : "=v"(r) : "v"(a), "v"(b));
  return r;
}

// ---------------------------------------------------------------------------
// k0: Wc = Wphi^T * Wpsi  (TN, f64 acc, f32 out) -- UNCHANGED (bitwise)
// ---------------------------------------------------------------------------
__global__ __launch_bounds__(256)
void k0_gemm_tn(const float* __restrict__ A, const float* __restrict__ B,
                float* __restrict__ C, int M, int N, int K) {
  __shared__ __align__(16) float As[32][68];
  __shared__ __align__(16) float Bs[32][68];
  const int tid = threadIdx.x;
  const int tx = tid & 15, ty = tid >> 4;
  const int brow = blockIdx.y << 6;
  const int bcol = blockIdx.x << 6;
  double acc[4][4] = {};
  for (int k0 = 0; k0 < K; k0 += 32) {
#pragma unroll
    for (int i = 0; i < 2; ++i) {
      const int f = tid + (i << 8);
      const int r = f >> 4;
      const int c4 = (f & 15) << 2;
      *reinterpret_cast<float4*>(&As[r][c4]) =
          *reinterpret_cast<const float4*>(&A[(size_t)(k0 + r) * M + brow + c4]);
      *reinterpret_cast<float4*>(&Bs[r][c4]) =
          *reinterpret_cast<const float4*>(&B[(size_t)(k0 + r) * N + bcol + c4]);
    }
    __syncthreads();
#pragma unroll
    for (int kk = 0; kk < 32; ++kk) {
      const float4 a = *reinterpret_cast<const float4*>(&As[kk][ty << 2]);
      const float4 b = *reinterpret_cast<const float4*>(&Bs[kk][tx << 2]);
      const double ad[4] = {a.x, a.y, a.z, a.w};
      const double bd[4] = {b.x, b.y, b.z, b.w};
#pragma unroll
      for (int i = 0; i < 4; ++i)
#pragma unroll
        for (int j = 0; j < 4; ++j)
          acc[i][j] = fma(ad[i], bd[j], acc[i][j]);
    }
    __syncthreads();
  }
#pragma unroll
  for (int i = 0; i < 4; ++i) {
    float4 v = make_float4((float)acc[i][0], (float)acc[i][1],
                           (float)acc[i][2], (float)acc[i][3]);
    *reinterpret_cast<float4*>(
        &C[(size_t)(brow + (ty << 2) + i) * N + bcol + (tx << 2)]) = v;
  }
}

// ---------------------------------------------------------------------------
// k1_fast: T = H * Wc (NN). Same f64 fma chain per output (k ascending,
// exact f32->f64 operands) => BITWISE-identical T.
// 128x128 tile, 8x8 micro, BK=16, f64 LDS staging, reg prefetch, XCD swizzle.
// Thread (tx=tid&15, ty=tid>>4): rows 8*ty+i, cols 2*tx+32*jj+h.
// ---------------------------------------------------------------------------
__global__ __launch_bounds__(256, 2)
void k1_fast(const float* __restrict__ A, const float* __restrict__ B,
             float* __restrict__ C) {
  __shared__ double As[128][17];   // [row][k], pad 17 (odd -> 2-way reads)
  __shared__ double Bs[16][130];   // [k][col], pad 130 (16B-aligned rows)
  const int tid = threadIdx.x;
  // bijective XCD swizzle (grid 8x64 = 512, 512%8==0)
  const int lin = blockIdx.y * 8 + blockIdx.x;
  const int nlin = (lin & 7) * 64 + (lin >> 3);
  const int bxi = nlin & 7, byi = nlin >> 3;
  const int brow = byi << 7;
  const int bcol = bxi << 7;
  const int tx = tid & 15, ty = tid >> 4;
  const int ar = tid >> 1, aks = (tid & 1) << 3;   // A staging: row, k-half
  const int bk = tid >> 4, btx = tid & 15;         // B staging: k-row, col-lane

  double acc[8][8];
#pragma unroll
  for (int i = 0; i < 8; ++i)
#pragma unroll
    for (int j = 0; j < 8; ++j) acc[i][j] = 0.0;

  const float* Aptr = &A[(size_t)(brow + ar) * DDIM + aks];
  const float* Bptr = &B[(size_t)bk * DDIM + bcol + (btx << 1)];

  float4 pa0, pa1;
  float2 pb[4];
  // preload k0 = 0
  pa0 = *reinterpret_cast<const float4*>(Aptr);
  pa1 = *reinterpret_cast<const float4*>(Aptr + 4);
#pragma unroll
  for (int w = 0; w < 4; ++w)
    pb[w] = *reinterpret_cast<const float2*>(Bptr + (w << 5));

  for (int k0 = 0; k0 < DDIM; k0 += 16) {
    __syncthreads();
    // stage (cvt f32->f64 once)
    As[ar][aks + 0] = (double)pa0.x; As[ar][aks + 1] = (double)pa0.y;
    As[ar][aks + 2] = (double)pa0.z; As[ar][aks + 3] = (double)pa0.w;
    As[ar][aks + 4] = (double)pa1.x; As[ar][aks + 5] = (double)pa1.y;
    As[ar][aks + 6] = (double)pa1.z; As[ar][aks + 7] = (double)pa1.w;
#pragma unroll
    for (int w = 0; w < 4; ++w) {
      Bs[bk][(btx << 1) + (w << 5) + 0] = (double)pb[w].x;
      Bs[bk][(btx << 1) + (w << 5) + 1] = (double)pb[w].y;
    }
    __syncthreads();
    // prefetch next K-step (hides global latency under the FMAs)
    if (k0 + 16 < DDIM) {
      pa0 = *reinterpret_cast<const float4*>(Aptr + k0 + 16);
      pa1 = *reinterpret_cast<const float4*>(Aptr + k0 + 20);
#pragma unroll
      for (int w = 0; w < 4; ++w)
        pb[w] = *reinterpret_cast<const float2*>(
            Bptr + (size_t)(k0 + 16) * DDIM + (w << 5));
    }
#pragma unroll 8
    for (int kk = 0; kk < 16; ++kk) {
      double a[8];
      double2 b[4];
#pragma unroll
      for (int i = 0; i < 8; ++i) a[i] = As[(ty << 3) + i][kk];
#pragma unroll
      for (int jj = 0; jj < 4; ++jj)
        b[jj] = *reinterpret_cast<const double2*>(&Bs[kk][(tx << 1) + (jj << 5)]);
#pragma unroll
      for (int i = 0; i < 8; ++i) {
#pragma unroll
        for (int jj = 0; jj < 4; ++jj) {
          acc[i][(jj << 1) + 0] = fma(a[i], b[jj].x, acc[i][(jj << 1) + 0]);
          acc[i][(jj << 1) + 1] = fma(a[i], b[jj].y, acc[i][(jj << 1) + 1]);
        }
      }
    }
  }
#pragma unroll
  for (int i = 0; i < 8; ++i) {
    float* crow = &C[(size_t)(brow + (ty << 3) + i) * DDIM + bcol + (tx << 1)];
#pragma unroll
    for (int jj = 0; jj < 4; ++jj) {
      float2 v = make_float2((float)acc[i][(jj << 1)],
                             (float)acc[i][(jj << 1) + 1]);
      *reinterpret_cast<float2*>(crow + (jj << 5)) = v;
    }
  }
}

// ---------------------------------------------------------------------------
// k2_mfma: approx scores = bf16(T) * bf16(H)^T, grid (16,16,4).
// 128x128 tile, 4 waves, BK=64, slot-XOR LDS swizzle, cvt in staging.
// Epilogue: 256-thread parallel per-row top-8 (scan 32 cols + exact merge).
// ---------------------------------------------------------------------------
__global__ __launch_bounds__(256)
void k2_mfma(const float* __restrict__ T, const float* __restrict__ H,
             unsigned short* __restrict__ cand_v,
             unsigned char* __restrict__ cand_i) {
  __shared__ union {
    unsigned short stage[2][128 * 64];
    float Sl[64][130];
    struct {
      float mv[256][8];
      unsigned char mi[256][8];
    } mg;
  } u;
  const int tid = threadIdx.x;
  const int lane = tid & 63;
  const int w = tid >> 6;
  const int wr = w >> 1, wc = w & 1;
  const int lr = lane & 15, lg = lane >> 4;
  const int z = blockIdx.z;
  const int brow = blockIdx.y << 7, bcol = blockIdx.x << 7;
  const int row0g = z * SEQ + brow;
  const int col0g = z * SEQ + bcol;

  f32x4 acc[4][4];
#pragma unroll
  for (int mi = 0; mi < 4; ++mi)
#pragma unroll
    for (int nj = 0; nj < 4; ++nj)
      acc[mi][nj] = (f32x4){0.f, 0.f, 0.f, 0.f};

  for (int k0 = 0; k0 < DDIM; k0 += 64) {
    __syncthreads();
#pragma unroll
    for (int q = 0; q < 4; ++q) {
      const int c = (q << 8) + tid;
      const int row = c >> 3, slot = c & 7;
      const int gs = slot ^ (row & 7);
      {
        const float* s = &T[(size_t)(row0g + row) * DDIM + k0 + (gs << 3)];
        const float4 f0 = *reinterpret_cast<const float4*>(s);
        const float4 f1 = *reinterpret_cast<const float4*>(s + 4);
        uint4 o;
        o.x = pkbf(f0.x, f0.y); o.y = pkbf(f0.z, f0.w);
        o.z = pkbf(f1.x, f1.y); o.w = pkbf(f1.z, f1.w);
        *reinterpret_cast<uint4*>(&u.stage[0][c << 3]) = o;
      }
      {
        const float* s = &H[(size_t)(col0g + row) * DDIM + k0 + (gs << 3)];
        const float4 f0 = *reinterpret_cast<const float4*>(s);
        const float4 f1 = *reinterpret_cast<const float4*>(s + 4);
        uint4 o;
        o.x = pkbf(f0.x, f0.y); o.y = pkbf(f0.z, f0.w);
        o.z = pkbf(f1.x, f1.y); o.w = pkbf(f1.z, f1.w);
        *reinterpret_cast<uint4*>(&u.stage[1][c << 3]) = o;
      }
    }
    __syncthreads();
#pragma unroll
    for (int kh = 0; kh < 2; ++kh) {
      bf16x8 af[4], bf[4];
      const int sl = (kh << 2) + lg;
#pragma unroll
      for (int mi = 0; mi < 4; ++mi) {
        const int ra = (wr << 6) + (mi << 4) + lr;
        af[mi] = *reinterpret_cast<const bf16x8*>(
            &u.stage[0][(ra << 6) + ((sl ^ (ra & 7)) << 3)]);
        const int rb = (wc << 6) + (mi << 4) + lr;
        bf[mi] = *reinterpret_cast<const bf16x8*>(
            &u.stage[1][(rb << 6) + ((sl ^ (rb & 7)) << 3)]);
      }
#pragma unroll
      for (int mi = 0; mi < 4; ++mi)
#pragma unroll
        for (int nj = 0; nj < 4; ++nj)
          acc[mi][nj] = __builtin_amdgcn_mfma_f32_16x16x32_bf16(
              af[mi], bf[nj], acc[mi][nj], 0, 0, 0);
    }
  }

  // epilogue: two 64-row phases; all 256 threads scan 32 cols, exact merge.
  const int bx = blockIdx.x;
  const int srow = tid >> 2;        // 0..63
  const int qd = tid & 3;           // quarter
  for (int p = 0; p < 2; ++p) {
    __syncthreads();
    if (wr == p) {
#pragma unroll
      for (int mi = 0; mi < 4; ++mi)
#pragma unroll
        for (int nj = 0; nj < 4; ++nj)
#pragma unroll
          for (int r = 0; r < 4; ++r)
            u.Sl[(mi << 4) + (lg << 2) + r][(wc << 6) + (nj << 4) + lr] =
                acc[mi][nj][r];
    }
    __syncthreads();
    // scan quarter (32 cols) into register top-8
    float v[KSEL];
    int ci[KSEL];
#pragma unroll
    for (int s = 0; s < KSEL; ++s) { v[s] = -3.0e38f; ci[s] = 0; }
    const int c0 = qd << 5;
    for (int c = 0; c < 32; ++c) {
      const float x = u.Sl[srow][c0 + c];
      if (x > v[KSEL - 1]) {
        float pv = x; int pc = c0 + c;
#pragma unroll
        for (int s = 0; s < KSEL; ++s) {
          if (x > v[s]) {
            const float tv = v[s]; const int tc = ci[s];
            v[s] = pv; ci[s] = pc; pv = tv; pc = tc;
          }
        }
      }
    }
    __syncthreads();   // all Sl reads done before mg overlay
#pragma unroll
    for (int s = 0; s < KSEL; ++s) {
      u.mg.mv[tid][s] = v[s];
      u.mg.mi[tid][s] = (unsigned char)ci[s];
    }
    __syncthreads();
    if (qd == 0) {
      // merge 4 quarter-lists in col-ascending order; strict > insertion
      // reproduces the (value desc, col asc) order of a full 0..127 scan.
      float fv[KSEL];
      int fi[KSEL];
#pragma unroll
      for (int s = 0; s < KSEL; ++s) { fv[s] = -3.0e38f; fi[s] = 0; }
#pragma unroll
      for (int t = 0; t < 4; ++t) {
#pragma unroll
        for (int s = 0; s < KSEL; ++s) {
          const float x = u.mg.mv[tid + t][s];
          const int idx = u.mg.mi[tid + t][s];
          if (x > fv[KSEL - 1]) {
            float pv = x; int pc = idx;
#pragma unroll
            for (int s2 = 0; s2 < KSEL; ++s2) {
              if (x > fv[s2]) {
                const float tv = fv[s2]; const int tc = fi[s2];
                fv[s2] = pv; fi[s2] = pc; pv = tv; pc = tc;
              }
            }
          }
        }
      }
      const size_t base =
          (size_t)(row0g + (p << 6) + srow) * 128 + ((size_t)bx << 3);
#pragma unroll
      for (int s = 0; s < KSEL; ++s) {
        cand_v[base + s] = f2bf(fv[s]);
        cand_i[base + s] = (unsigned char)fi[s];
      }
    }
  }
}

// ---------------------------------------------------------------------------
// kr_rescore: fused extraction (approx-top-16) + exact f64 rescore + stable
// top-8 + weights + self-loop count. One wave per row. -- UNCHANGED
// ---------------------------------------------------------------------------
__global__ __launch_bounds__(256)
void kr_rescore(const float* __restrict__ T, const float* __restrict__ H,
                const unsigned short* __restrict__ cand_v,
                const unsigned char* __restrict__ cand_i,
                int* __restrict__ topi, float* __restrict__ topw,
                int* __restrict__ cnt) {
  const int tid = threadIdx.x, lane = tid & 63, w = tid >> 6;
  const int r = blockIdx.x * 4 + w;
  const int b = r >> 11, iloc = r & (SEQ - 1);

  const size_t cbase = (size_t)r * 128;
  const int s0 = lane << 1, s1 = s0 + 1;
  float v0 = bf2f(cand_v[cbase + s0]);
  float v1 = bf2f(cand_v[cbase + s1]);
  int i0 = ((s0 >> 3) << 7) + cand_i[cbase + s0];
  int i1 = ((s1 >> 3) << 7) + cand_i[cbase + s1];
  if (v1 > v0) {
    const float tv = v0; v0 = v1; v1 = tv;
    const int ti = i0; i0 = i1; i1 = ti;
  }
  int keep = 0;
  for (int rnd = 0; rnd < 16; ++rnd) {
    float m = v0;
#pragma unroll
    for (int off = 32; off >= 1; off >>= 1) m = fmaxf(m, __shfl_xor(m, off));
    const unsigned long long bm = __ballot(v0 == m);
    const int owner = __ffsll(bm) - 1;
    const int oi = __shfl(i0, owner);
    if (lane == owner) { v0 = v1; i0 = i1; v1 = -3.0e38f; }
    if (lane == rnd) keep = oi;
  }

  const float* Trow = T + (size_t)r * DDIM;
  float4 t4[4];
#pragma unroll
  for (int q = 0; q < 4; ++q)
    t4[q] = *reinterpret_cast<const float4*>(&Trow[(q << 8) + (lane << 2)]);

  float t8v[KSEL];
  int t8i[KSEL];
#pragma unroll
  for (int p = 0; p < KSEL; ++p) { t8v[p] = -1.0f; t8i[p] = IMAXC; }

  for (int c = 0; c < 16; ++c) {
    const int j = __shfl(keep, c);
    const float* Hrow = H + ((size_t)(b << 11) + j) * DDIM;
    double s = 0.0;
#pragma unroll
    for (int q = 0; q < 4; ++q) {
      const float4 h = *reinterpret_cast<const float4*>(&Hrow[(q << 8) + (lane << 2)]);
      s = fma((double)t4[q].x, (double)h.x, s);
      s = fma((double)t4[q].y, (double)h.y, s);
      s = fma((double)t4[q].z, (double)h.z, s);
      s = fma((double)t4[q].w, (double)h.w, s);
    }
#pragma unroll
    for (int off = 1; off < 64; off <<= 1) s += __shfl_xor(s, off);
    const float aff = expf((float)s);
    const bool g7 = (aff > t8v[KSEL - 1]) ||
                    (aff == t8v[KSEL - 1] && j < t8i[KSEL - 1]);
    if (g7) {
      float pv = aff; int pi = j;
#pragma unroll
      for (int p = 0; p < KSEL; ++p) {
        const bool g = (aff > t8v[p]) || (aff == t8v[p] && j < t8i[p]);
        if (g) {
          const float tv = t8v[p]; const int ti = t8i[p];
          t8v[p] = pv; t8i[p] = pi; pv = tv; pi = ti;
        }
      }
    }
  }
  if (lane == 0) {
    float sum = 0.0f;
#pragma unroll
    for (int p = 0; p < KSEL; ++p) sum += t8v[p];
    sum += 1e-8f;
    int c8 = KSEL;
#pragma unroll
    for (int p = 0; p < KSEL; ++p)
      if (t8i[p] == iloc) --c8;
    cnt[r] = c8;
#pragma unroll
    for (int p = 0; p < KSEL; ++p) {
      topi[(size_t)r * KSEL + p] = t8i[p];
      topw[(size_t)r * KSEL + p] = t8v[p] / sum;
    }
  }
}

// ---------------------------------------------------------------------------
// k4: exclusive prefix scan of per-row counts  -- UNCHANGED
// ---------------------------------------------------------------------------
__global__ __launch_bounds__(1024)
void k4_scan(const int* __restrict__ cnt, int* __restrict__ off) {
  __shared__ int part[1024];
  const int t = threadIdx.x;
  int loc[8];
  int s = 0;
#pragma unroll
  for (int i = 0; i < 8; ++i) { loc[i] = s; s += cnt[t * 8 + i]; }
  part[t] = s;
  __syncthreads();
  for (int d = 1; d < 1024; d <<= 1) {
    const int add = (t >= d) ? part[t - d] : 0;
    __syncthreads();
    part[t] += add;
    __syncthreads();
  }
  const int base = (t == 0) ? 0 : part[t - 1];
#pragma unroll
  for (int i = 0; i < 8; ++i) off[t * 8 + i] = base + loc[i];
}

// ---------------------------------------------------------------------------
// k5: emit edges  -- UNCHANGED
// ---------------------------------------------------------------------------
__global__ __launch_bounds__(256)
void k5_emit(const int* __restrict__ topi, const float* __restrict__ topw,
             const int* __restrict__ off, float* __restrict__ out, int E) {
  const int r = blockIdx.x * 256 + threadIdx.x;
  if (r >= NROWS) return;
  const int o = off[r];
  const int sloc = r & (SEQ - 1);
  const int bbase = r & ~(SEQ - 1);
  int e = 0;
#pragma unroll
  for (int p = 0; p < KSEL; ++p) {
    const int id = topi[(size_t)r * KSEL + p];
    const float w = topw[(size_t)r * KSEL + p];
    if (id != sloc) {
      const int pos = o + e;
      if (pos < E) {
        out[pos] = (float)r;
        out[(size_t)E + pos] = (float)(bbase + id);
        out[2 * (size_t)E + pos] = w;
      }
      ++e;
    }
  }
}

// ---------------------------------------------------------------------------
extern "C" void kernel_launch(void* const* d_in, const int* in_sizes, int n_in,
                              void* d_out, int out_size, void* d_ws,
                              size_t ws_size, hipStream_t stream) {
  const float* H = (const float*)d_in[0];      // [4,2048,1024]
  const float* Wphi = (const float*)d_in[1];   // [1024,1024]
  const float* Wpsi = (const float*)d_in[2];   // [1024,1024]
  float* out = (float*)d_out;
  const int E = out_size / 3;

  char* base = (char*)d_ws;
  float* T = (float*)base;                         // 32 MB
  char* regionX = base + 33554432;                 // 4 MB shared region
  float* Wc = (float*)regionX;                     //   Wc (dead after k1)
  unsigned short* cand_v = (unsigned short*)regionX;           // 2 MB
  unsigned char* cand_i = (unsigned char*)(regionX + 2097152); // 1 MB
  char* pp = regionX + 4194304;
  int* topi = (int*)pp;  pp += 262144;
  float* topw = (float*)pp; pp += 262144;
  int* cnt = (int*)pp;   pp += 32768;
  int* off = (int*)pp;

  // Wc = Wphi^T * Wpsi
  k0_gemm_tn<<<dim3(16, 16), 256, 0, stream>>>(Wphi, Wpsi, Wc, 1024, 1024, 1024);
  // T = H * Wc  (bitwise-identical values; defines the exact ranking)
  k1_fast<<<dim3(8, 64), 256, 0, stream>>>(H, Wc, T);
  // approx MFMA scores + fused block-top-8 (Wc dead; cand reuses its region)
  k2_mfma<<<dim3(16, 16, 4), 256, 0, stream>>>(T, H, cand_v, cand_i);
  // fused extraction + exact f64 rescore + stable top-8 + weights + counts
  kr_rescore<<<dim3(NROWS / 4), 256, 0, stream>>>(T, H, cand_v, cand_i,
                                                  topi, topw, cnt);
  // prefix scan + emit
  k4_scan<<<dim3(1), 1024, 0, stream>>>(cnt, off);
  k5_emit<<<dim3(NROWS / 256), 256, 0, stream>>>(topi, topw, off, out, E);
}